// Round 5
// baseline (254.408 us; speedup 1.0000x reference)
//
#include <hip/hip_runtime.h>
#include <hip/hip_bf16.h>

// InfoNCE fused: loss = (1/N) sum_i [ log(sum_j exp(sim_ij)) - sim_ii ]
// sim = (z1/||z1||)@(z2/||z2||)^T / tau.  logits=[pos, diag-masked row] with
// pos == sim_ii => lse over the FULL row (diagonal included).
//
// z1f = bf16(z1n * log2(e)/tau) so exp(sim) = exp2(MFMA output); values in
// [-29,29] in log2 domain -> raw v_exp_f32 (__builtin_amdgcn_exp2f), NOT libm.
//
// R5 vs R4 (57.4 us main, VALUBusy 54%):
//  - zero-C MFMA (no per-tile acc re-zeroing: -16 v_mov/tile)
//  - diagonal handled in norm kernel (posv = in-register row dot) ->
//    branch-free inner loop
//  - explicit 2-tile-ahead register prefetch of B fragments
//  - finalize fused into main via last-block-done (one fewer dispatch)

typedef __bf16  bf16x8 __attribute__((ext_vector_type(8)));
typedef __bf16  bf16x4 __attribute__((ext_vector_type(4)));
typedef float   f32x4  __attribute__((ext_vector_type(4)));

#if __has_builtin(__builtin_amdgcn_exp2f)
#define EXP2F(x) __builtin_amdgcn_exp2f(x)   // raw v_exp_f32
#else
#define EXP2F(x) exp2f(x)
#endif
#if __has_builtin(__builtin_amdgcn_logf)
#define LOG2F(x) __builtin_amdgcn_logf(x)    // raw v_log_f32
#else
#define LOG2F(x) log2f(x)
#endif

#define DDIM   64
#define TILEB  2048         // bytes per fragment-ordered 16-col tile
#define NSETS  4            // 16-row MFMA sets per wave (64 rows/wave)
#define NW     4            // waves per block
#define BM     (NW * NSETS * 16)   // 256 rows per block
#define CS     32           // column splits -> grid (64,32) = 2048 blocks

// ---------------------------------------------------------------- normalize
// One block per 16-row tile. Thread (r = tid>>4, c = tid&15) loads
// z[row, 4c..4c+4), reduces ||row|| over its 16-lane group, writes the 4
// bf16 values into fragment order:
//   byte off(tile) = (c>>3)*1024 + ((c>>1)&3)*256 + r*16 + (c&1)*8
// Since the SAME thread holds row i of both views, it also computes
// posv[i] = dot(z1f_i, z2f_i) from the bf16-rounded values (matches the
// MFMA diagonal term closely). Also zeroes rowsum and the done counter.
__global__ __launch_bounds__(256) void norm_frag_kernel(
    const float* __restrict__ z1, const float* __restrict__ z2,
    __hip_bfloat16* __restrict__ z1f, __hip_bfloat16* __restrict__ z2f,
    float* __restrict__ rowsum, float* __restrict__ posv,
    int* __restrict__ donecnt, float scale1, int N)
{
    const int tid  = threadIdx.x;
    const int r    = tid >> 4, c = tid & 15;
    const int tile = blockIdx.x;
    const size_t row = (size_t)tile * 16 + r;
    const size_t off = (size_t)tile * TILEB
                     + ((c >> 3) << 10) + (((c >> 1) & 3) << 8)
                     + (r << 4) + ((c & 1) << 3);

    bf16x4 o1, o2;
    // z1 (scaled by log2(e)/tau)
    {
        float4 v = *(const float4*)(z1 + row * DDIM + c * 4);
        float ss = v.x*v.x + v.y*v.y + v.z*v.z + v.w*v.w;
        #pragma unroll
        for (int o = 8; o; o >>= 1) ss += __shfl_xor(ss, o);
        float inv = scale1 / fmaxf(sqrtf(ss), 1e-12f);
        o1 = (bf16x4){ __float2bfloat16(v.x*inv), __float2bfloat16(v.y*inv),
                       __float2bfloat16(v.z*inv), __float2bfloat16(v.w*inv) };
        *(bf16x4*)((char*)z1f + off) = o1;
    }
    // z2 (unit scale)
    {
        float4 v = *(const float4*)(z2 + row * DDIM + c * 4);
        float ss = v.x*v.x + v.y*v.y + v.z*v.z + v.w*v.w;
        #pragma unroll
        for (int o = 8; o; o >>= 1) ss += __shfl_xor(ss, o);
        float inv = 1.0f / fmaxf(sqrtf(ss), 1e-12f);
        o2 = (bf16x4){ __float2bfloat16(v.x*inv), __float2bfloat16(v.y*inv),
                       __float2bfloat16(v.z*inv), __float2bfloat16(v.w*inv) };
        *(bf16x4*)((char*)z2f + off) = o2;
    }

    // posv[row] = dot of the bf16-rounded rows (log2-domain positive logit)
    float p = (float)o1[0]*(float)o2[0] + (float)o1[1]*(float)o2[1]
            + (float)o1[2]*(float)o2[2] + (float)o1[3]*(float)o2[3];
    #pragma unroll
    for (int o = 8; o; o >>= 1) p += __shfl_xor(p, o);
    if (c == 0) posv[row] = p;

    if (tid < 16) rowsum[(size_t)tile * 16 + tid] = 0.f;
    if (tile == 0 && tid == 0) *donecnt = 0;
}

// ---------------------------------------------------------------- main
__global__ __launch_bounds__(256, 5) void infonce_main_kernel(
    const __hip_bfloat16* __restrict__ z1f,
    const __hip_bfloat16* __restrict__ z2f,
    float* __restrict__ rowsum,    // fp32, atomic partial rowsums of 2^C
    const float* __restrict__ posv,
    int* __restrict__ donecnt,
    float* __restrict__ out, int N)
{
    const int tid  = threadIdx.x;
    const int wave = tid >> 6;
    const int lane = tid & 63;
    const int q    = lane >> 4;
    const int l15  = lane & 15;

    const int colspan = N / CS;
    const int ntiles  = colspan >> 4;
    const int c0      = blockIdx.y * colspan;
    const int wr      = blockIdx.x * BM + wave * (NSETS * 16);

    // A fragments for NSETS row-tiles (coalesced: fragment-ordered global)
    bf16x8 a0[NSETS], a1[NSETS];
    #pragma unroll
    for (int s = 0; s < NSETS; ++s) {
        const char* ab = (const char*)z1f + (size_t)((wr >> 4) + s) * TILEB + lane * 16;
        a0[s] = *(const bf16x8*)(ab);
        a1[s] = *(const bf16x8*)(ab + 1024);
    }

    float sum[NSETS * 4];
    #pragma unroll
    for (int k = 0; k < NSETS * 4; ++k) sum[k] = 0.f;

    const char* bbase = (const char*)z2f + (size_t)(c0 >> 4) * TILEB + lane * 16;
    const f32x4 kzero = {0.f, 0.f, 0.f, 0.f};

    // rotating 2-tile register prefetch
    bf16x8 b0a = *(const bf16x8*)(bbase);
    bf16x8 b1a = *(const bf16x8*)(bbase + 1024);
    bf16x8 b0b = *(const bf16x8*)(bbase + TILEB);
    bf16x8 b1b = *(const bf16x8*)(bbase + TILEB + 1024);

    for (int t = 0; t < ntiles; t += 2) {
        // issue next 2 tiles' loads (clamped in-range; waits happen 2 tiles later)
        const char* pa = bbase + (size_t)((t + 2 < ntiles) ? t + 2 : 0) * TILEB;
        const char* pb = bbase + (size_t)((t + 3 < ntiles) ? t + 3 : 0) * TILEB;
        bf16x8 n0 = *(const bf16x8*)(pa);
        bf16x8 n1 = *(const bf16x8*)(pa + 1024);
        bf16x8 n2 = *(const bf16x8*)(pb);
        bf16x8 n3 = *(const bf16x8*)(pb + 1024);

        #pragma unroll
        for (int s = 0; s < NSETS; ++s) {
            f32x4 acc = __builtin_amdgcn_mfma_f32_16x16x32_bf16(a0[s], b0a, kzero, 0, 0, 0);
            acc = __builtin_amdgcn_mfma_f32_16x16x32_bf16(a1[s], b1a, acc, 0, 0, 0);
            sum[s * 4 + 0] += EXP2F(acc[0]);
            sum[s * 4 + 1] += EXP2F(acc[1]);
            sum[s * 4 + 2] += EXP2F(acc[2]);
            sum[s * 4 + 3] += EXP2F(acc[3]);
        }
        #pragma unroll
        for (int s = 0; s < NSETS; ++s) {
            f32x4 acc = __builtin_amdgcn_mfma_f32_16x16x32_bf16(a0[s], b0b, kzero, 0, 0, 0);
            acc = __builtin_amdgcn_mfma_f32_16x16x32_bf16(a1[s], b1b, acc, 0, 0, 0);
            sum[s * 4 + 0] += EXP2F(acc[0]);
            sum[s * 4 + 1] += EXP2F(acc[1]);
            sum[s * 4 + 2] += EXP2F(acc[2]);
            sum[s * 4 + 3] += EXP2F(acc[3]);
        }
        b0a = n0; b1a = n1; b0b = n2; b1b = n3;
    }

    // reduce each row-sum across the 16 lanes of the quad, then atomics
    #pragma unroll
    for (int k = 0; k < NSETS * 4; ++k) {
        float v = sum[k];
        #pragma unroll
        for (int o = 1; o < 16; o <<= 1) v += __shfl_xor(v, o);
        sum[k] = v;
    }
    if (l15 == 0) {
        #pragma unroll
        for (int s = 0; s < NSETS; ++s)
            #pragma unroll
            for (int i = 0; i < 4; ++i)
                atomicAdd(&rowsum[wr + s * 16 + q * 4 + i], sum[s * 4 + i]);
    }

    // ---- last-block-done finalize (saves a dispatch)
    __threadfence();
    __shared__ int slast;
    if (tid == 0) {
        int done = atomicAdd(donecnt, 1);
        slast = (done == (int)(gridDim.x * gridDim.y) - 1) ? 1 : 0;
    }
    __syncthreads();
    if (slast) {
        __threadfence();   // acquire side
        float acc = 0.f;
        for (int row = tid; row < N; row += 256) {
            float s = __hip_atomic_load(&rowsum[row], __ATOMIC_RELAXED,
                                        __HIP_MEMORY_SCOPE_AGENT);
            acc += LOG2F(s) - posv[row];
        }
        #pragma unroll
        for (int o = 32; o; o >>= 1) acc += __shfl_xor(acc, o);
        __shared__ float red[NW];
        if (lane == 0) red[wave] = acc;
        __syncthreads();
        if (tid == 0)
            *out = 0.69314718055994531f * (red[0] + red[1] + red[2] + red[3])
                 / (float)N;
    }
}

// ---------------------------------------------------------------- launch
extern "C" void kernel_launch(void* const* d_in, const int* in_sizes, int n_in,
                              void* d_out, int out_size, void* d_ws, size_t ws_size,
                              hipStream_t stream)
{
    const float* z1 = (const float*)d_in[0];
    const float* z2 = (const float*)d_in[1];
    const int N = in_sizes[0] / DDIM;   // 16384

    char* ws = (char*)d_ws;
    __hip_bfloat16* z1f = (__hip_bfloat16*)ws;                  // N*128 B (2 MB)
    __hip_bfloat16* z2f = z1f + (size_t)N * DDIM;               // N*128 B (2 MB)
    float* rowsum  = (float*)(ws + 2 * (size_t)N * DDIM * 2);   // N*4 B
    float* posv    = rowsum + N;                                // N*4 B
    int*   donecnt = (int*)(posv + N);                          // 4 B

    const float kScale = 28.853900817779268f;   // log2(e) / 0.05

    norm_frag_kernel<<<N / 16, 256, 0, stream>>>(z1, z2, z1f, z2f, rowsum,
                                                 posv, donecnt, kScale, N);

    dim3 grid(N / BM, CS);
    infonce_main_kernel<<<grid, NW * 64, 0, stream>>>(z1f, z2f, rowsum, posv,
                                                      donecnt, (float*)d_out, N);
}

// Round 6
// 111.032 us; speedup vs baseline: 2.2913x; 2.2913x over previous
//
#include <hip/hip_runtime.h>
#include <hip/hip_bf16.h>

// InfoNCE fused: loss = (1/N) sum_i [ log(sum_j exp(sim_ij)) - sim_ii ]
// sim = (z1/||z1||)@(z2/||z2||)^T / tau.  logits=[pos, diag-masked row] with
// pos == sim_ii => lse over the FULL row (diagonal included).
//
// z1f = bf16(z1n * log2(e)/tau) so exp(sim) = exp2(MFMA output); values in
// [-29,29] in log2 domain -> raw v_exp_f32 (__builtin_amdgcn_exp2f), NOT libm.
//
// R6: revert R5's fused finalize (per-block __threadfence = 2048x buffer_wbl2
// L2 writebacks -> 204 us; dispatch boundary is the cheap ordering). Keep:
// zero-C MFMA, branch-free inner loop (posv from norm kernel), LDS-free
// fragment-ordered global layout. Let the compiler schedule loads (unroll 4).

typedef __bf16  bf16x8 __attribute__((ext_vector_type(8)));
typedef __bf16  bf16x4 __attribute__((ext_vector_type(4)));
typedef float   f32x4  __attribute__((ext_vector_type(4)));

#if __has_builtin(__builtin_amdgcn_exp2f)
#define EXP2F(x) __builtin_amdgcn_exp2f(x)   // raw v_exp_f32
#else
#define EXP2F(x) exp2f(x)
#endif
#if __has_builtin(__builtin_amdgcn_logf)
#define LOG2F(x) __builtin_amdgcn_logf(x)    // raw v_log_f32
#else
#define LOG2F(x) log2f(x)
#endif

#define DDIM   64
#define TILEB  2048         // bytes per fragment-ordered 16-col tile
#define NSETS  4            // 16-row MFMA sets per wave (64 rows/wave)
#define NW     4            // waves per block
#define BM     (NW * NSETS * 16)   // 256 rows per block
#define CS     32           // column splits -> grid (64,32) = 2048 blocks

// ---------------------------------------------------------------- normalize
// One block per 16-row tile. Thread (r = tid>>4, c = tid&15) loads
// z[row, 4c..4c+4), reduces ||row|| over its 16-lane group, writes the 4
// bf16 values into fragment order:
//   byte off(tile) = (c>>3)*1024 + ((c>>1)&3)*256 + r*16 + (c&1)*8
// Same thread holds row i of both views -> posv[i] = dot(z1f_i, z2f_i)
// computed here (bf16-rounded, matches MFMA diagonal). Zeroes rowsum.
__global__ __launch_bounds__(256) void norm_frag_kernel(
    const float* __restrict__ z1, const float* __restrict__ z2,
    __hip_bfloat16* __restrict__ z1f, __hip_bfloat16* __restrict__ z2f,
    float* __restrict__ rowsum, float* __restrict__ posv,
    float scale1, int N)
{
    const int tid  = threadIdx.x;
    const int r    = tid >> 4, c = tid & 15;
    const int tile = blockIdx.x;
    const size_t row = (size_t)tile * 16 + r;
    const size_t off = (size_t)tile * TILEB
                     + ((c >> 3) << 10) + (((c >> 1) & 3) << 8)
                     + (r << 4) + ((c & 1) << 3);

    bf16x4 o1, o2;
    // z1 (scaled by log2(e)/tau)
    {
        float4 v = *(const float4*)(z1 + row * DDIM + c * 4);
        float ss = v.x*v.x + v.y*v.y + v.z*v.z + v.w*v.w;
        #pragma unroll
        for (int o = 8; o; o >>= 1) ss += __shfl_xor(ss, o);
        float inv = scale1 / fmaxf(sqrtf(ss), 1e-12f);
        o1 = (bf16x4){ __float2bfloat16(v.x*inv), __float2bfloat16(v.y*inv),
                       __float2bfloat16(v.z*inv), __float2bfloat16(v.w*inv) };
        *(bf16x4*)((char*)z1f + off) = o1;
    }
    // z2 (unit scale)
    {
        float4 v = *(const float4*)(z2 + row * DDIM + c * 4);
        float ss = v.x*v.x + v.y*v.y + v.z*v.z + v.w*v.w;
        #pragma unroll
        for (int o = 8; o; o >>= 1) ss += __shfl_xor(ss, o);
        float inv = 1.0f / fmaxf(sqrtf(ss), 1e-12f);
        o2 = (bf16x4){ __float2bfloat16(v.x*inv), __float2bfloat16(v.y*inv),
                       __float2bfloat16(v.z*inv), __float2bfloat16(v.w*inv) };
        *(bf16x4*)((char*)z2f + off) = o2;
    }

    // posv[row] = dot of the bf16-rounded rows (log2-domain positive logit)
    float p = (float)o1[0]*(float)o2[0] + (float)o1[1]*(float)o2[1]
            + (float)o1[2]*(float)o2[2] + (float)o1[3]*(float)o2[3];
    #pragma unroll
    for (int o = 8; o; o >>= 1) p += __shfl_xor(p, o);
    if (c == 0) posv[row] = p;

    if (tid < 16) rowsum[(size_t)tile * 16 + tid] = 0.f;
}

// ---------------------------------------------------------------- main
__global__ __launch_bounds__(256, 8) void infonce_main_kernel(
    const __hip_bfloat16* __restrict__ z1f,
    const __hip_bfloat16* __restrict__ z2f,
    float* __restrict__ rowsum,    // fp32, atomic partial rowsums of 2^C
    int N)
{
    const int tid  = threadIdx.x;
    const int wave = tid >> 6;
    const int lane = tid & 63;
    const int q    = lane >> 4;
    const int l15  = lane & 15;

    const int colspan = N / CS;
    const int ntiles  = colspan >> 4;
    const int c0      = blockIdx.y * colspan;
    const int wr      = blockIdx.x * BM + wave * (NSETS * 16);

    // A fragments for NSETS row-tiles (coalesced: fragment-ordered global)
    bf16x8 a0[NSETS], a1[NSETS];
    #pragma unroll
    for (int s = 0; s < NSETS; ++s) {
        const char* ab = (const char*)z1f + (size_t)((wr >> 4) + s) * TILEB + lane * 16;
        a0[s] = *(const bf16x8*)(ab);
        a1[s] = *(const bf16x8*)(ab + 1024);
    }

    float sum[NSETS * 4];
    #pragma unroll
    for (int k = 0; k < NSETS * 4; ++k) sum[k] = 0.f;

    const char* bptr = (const char*)z2f + (size_t)(c0 >> 4) * TILEB + lane * 16;
    const f32x4 kzero = {0.f, 0.f, 0.f, 0.f};

    #pragma unroll 4
    for (int t = 0; t < ntiles; ++t) {
        bf16x8 b0 = *(const bf16x8*)(bptr);
        bf16x8 b1 = *(const bf16x8*)(bptr + 1024);
        bptr += TILEB;
        #pragma unroll
        for (int s = 0; s < NSETS; ++s) {
            f32x4 acc = __builtin_amdgcn_mfma_f32_16x16x32_bf16(a0[s], b0, kzero, 0, 0, 0);
            acc = __builtin_amdgcn_mfma_f32_16x16x32_bf16(a1[s], b1, acc, 0, 0, 0);
            sum[s * 4 + 0] += EXP2F(acc[0]);
            sum[s * 4 + 1] += EXP2F(acc[1]);
            sum[s * 4 + 2] += EXP2F(acc[2]);
            sum[s * 4 + 3] += EXP2F(acc[3]);
        }
    }

    // reduce each row-sum across the 16 lanes of the quad, then atomics
    #pragma unroll
    for (int k = 0; k < NSETS * 4; ++k) {
        float v = sum[k];
        #pragma unroll
        for (int o = 1; o < 16; o <<= 1) v += __shfl_xor(v, o);
        sum[k] = v;
    }
    if (l15 == 0) {
        #pragma unroll
        for (int s = 0; s < NSETS; ++s)
            #pragma unroll
            for (int i = 0; i < 4; ++i)
                atomicAdd(&rowsum[wr + s * 16 + q * 4 + i], sum[s * 4 + i]);
    }
}

// ---------------------------------------------------------------- finalize
// 64 blocks x 256 threads: thread t handles one row.
__global__ __launch_bounds__(256) void finalize_kernel(
    const float* __restrict__ rowsum, const float* __restrict__ posv,
    float* __restrict__ out, int N)
{
    int row = blockIdx.x * 256 + threadIdx.x;
    float acc = (LOG2F(rowsum[row]) - posv[row]) * (0.69314718055994531f / (float)N);
    #pragma unroll
    for (int o = 32; o; o >>= 1) acc += __shfl_xor(acc, o);
    if ((threadIdx.x & 63) == 0) atomicAdd(out, acc);
}

// ---------------------------------------------------------------- launch
extern "C" void kernel_launch(void* const* d_in, const int* in_sizes, int n_in,
                              void* d_out, int out_size, void* d_ws, size_t ws_size,
                              hipStream_t stream)
{
    const float* z1 = (const float*)d_in[0];
    const float* z2 = (const float*)d_in[1];
    const int N = in_sizes[0] / DDIM;   // 16384

    char* ws = (char*)d_ws;
    __hip_bfloat16* z1f = (__hip_bfloat16*)ws;                  // N*128 B (2 MB)
    __hip_bfloat16* z2f = z1f + (size_t)N * DDIM;               // N*128 B (2 MB)
    float* rowsum = (float*)(ws + 2 * (size_t)N * DDIM * 2);    // N*4 B
    float* posv   = rowsum + N;                                 // N*4 B

    const float kScale = 28.853900817779268f;   // log2(e) / 0.05

    hipMemsetAsync(d_out, 0, sizeof(float), stream);

    norm_frag_kernel<<<N / 16, 256, 0, stream>>>(z1, z2, z1f, z2f, rowsum,
                                                 posv, kScale, N);

    dim3 grid(N / BM, CS);
    infonce_main_kernel<<<grid, NW * 64, 0, stream>>>(z1f, z2f, rowsum, N);

    finalize_kernel<<<N / 256, 256, 0, stream>>>(rowsum, posv, (float*)d_out, N);
}

// Round 7
// 106.374 us; speedup vs baseline: 2.3916x; 1.0438x over previous
//
#include <hip/hip_runtime.h>
#include <hip/hip_bf16.h>

// InfoNCE fused: loss = (1/N) sum_i [ log(sum_j exp(sim_ij)) - sim_ii ]
// sim = (z1/||z1||)@(z2/||z2||)^T / tau.  logits=[pos, diag-masked row] with
// pos == sim_ii => lse over the FULL row (diagonal included).
//
// z1f = bf16(z1n * log2(e)/tau) so exp(sim) = exp2(MFMA output); values in
// [-29,29] in log2 domain -> raw v_exp_f32 (__builtin_amdgcn_exp2f), NOT libm.
//
// R7 vs R6 (50.8 us main): __launch_bounds__(256,8) capped VGPRs at 32 ->
// A-fragments rematerialized, loads serialized (VALUBusy fell to 43%).
// Switch to (256,4): 128-VGPR budget, everything resident, measured
// occupancy was ~4 waves/SIMD anyway so no TLP loss. Memset folded into norm.

typedef __bf16  bf16x8 __attribute__((ext_vector_type(8)));
typedef __bf16  bf16x4 __attribute__((ext_vector_type(4)));
typedef float   f32x4  __attribute__((ext_vector_type(4)));

#if __has_builtin(__builtin_amdgcn_exp2f)
#define EXP2F(x) __builtin_amdgcn_exp2f(x)   // raw v_exp_f32
#else
#define EXP2F(x) exp2f(x)
#endif
#if __has_builtin(__builtin_amdgcn_logf)
#define LOG2F(x) __builtin_amdgcn_logf(x)    // raw v_log_f32
#else
#define LOG2F(x) log2f(x)
#endif

#define DDIM   64
#define TILEB  2048         // bytes per fragment-ordered 16-col tile
#define NSETS  4            // 16-row MFMA sets per wave (64 rows/wave)
#define NW     4            // waves per block
#define BM     (NW * NSETS * 16)   // 256 rows per block
#define CS     32           // column splits -> grid (64,32) = 2048 blocks

// ---------------------------------------------------------------- normalize
// One block per 16-row tile. Thread (r = tid>>4, c = tid&15) loads
// z[row, 4c..4c+4), reduces ||row|| over its 16-lane group, writes the 4
// bf16 values into fragment order:
//   byte off(tile) = (c>>3)*1024 + ((c>>1)&3)*256 + r*16 + (c&1)*8
// Same thread holds row i of both views -> posv[i] = dot(z1f_i, z2f_i)
// computed here (bf16-rounded, matches MFMA diagonal). Zeroes rowsum; block 0
// zeroes d_out (stream-ordered before finalize's atomics).
__global__ __launch_bounds__(256) void norm_frag_kernel(
    const float* __restrict__ z1, const float* __restrict__ z2,
    __hip_bfloat16* __restrict__ z1f, __hip_bfloat16* __restrict__ z2f,
    float* __restrict__ rowsum, float* __restrict__ posv,
    float* __restrict__ out, float scale1, int N)
{
    const int tid  = threadIdx.x;
    const int r    = tid >> 4, c = tid & 15;
    const int tile = blockIdx.x;
    const size_t row = (size_t)tile * 16 + r;
    const size_t off = (size_t)tile * TILEB
                     + ((c >> 3) << 10) + (((c >> 1) & 3) << 8)
                     + (r << 4) + ((c & 1) << 3);

    bf16x4 o1, o2;
    // z1 (scaled by log2(e)/tau)
    {
        float4 v = *(const float4*)(z1 + row * DDIM + c * 4);
        float ss = v.x*v.x + v.y*v.y + v.z*v.z + v.w*v.w;
        #pragma unroll
        for (int o = 8; o; o >>= 1) ss += __shfl_xor(ss, o);
        float inv = scale1 / fmaxf(sqrtf(ss), 1e-12f);
        o1 = (bf16x4){ __float2bfloat16(v.x*inv), __float2bfloat16(v.y*inv),
                       __float2bfloat16(v.z*inv), __float2bfloat16(v.w*inv) };
        *(bf16x4*)((char*)z1f + off) = o1;
    }
    // z2 (unit scale)
    {
        float4 v = *(const float4*)(z2 + row * DDIM + c * 4);
        float ss = v.x*v.x + v.y*v.y + v.z*v.z + v.w*v.w;
        #pragma unroll
        for (int o = 8; o; o >>= 1) ss += __shfl_xor(ss, o);
        float inv = 1.0f / fmaxf(sqrtf(ss), 1e-12f);
        o2 = (bf16x4){ __float2bfloat16(v.x*inv), __float2bfloat16(v.y*inv),
                       __float2bfloat16(v.z*inv), __float2bfloat16(v.w*inv) };
        *(bf16x4*)((char*)z2f + off) = o2;
    }

    // posv[row] = dot of the bf16-rounded rows (log2-domain positive logit)
    float p = (float)o1[0]*(float)o2[0] + (float)o1[1]*(float)o2[1]
            + (float)o1[2]*(float)o2[2] + (float)o1[3]*(float)o2[3];
    #pragma unroll
    for (int o = 8; o; o >>= 1) p += __shfl_xor(p, o);
    if (c == 0) posv[row] = p;

    if (tid < 16) rowsum[(size_t)tile * 16 + tid] = 0.f;
    if (tile == 0 && tid == 0) *out = 0.f;
}

// ---------------------------------------------------------------- main
__global__ __launch_bounds__(256, 4) void infonce_main_kernel(
    const __hip_bfloat16* __restrict__ z1f,
    const __hip_bfloat16* __restrict__ z2f,
    float* __restrict__ rowsum,    // fp32, atomic partial rowsums of 2^C
    int N)
{
    const int tid  = threadIdx.x;
    const int wave = tid >> 6;
    const int lane = tid & 63;
    const int q    = lane >> 4;
    const int l15  = lane & 15;

    const int colspan = N / CS;
    const int ntiles  = colspan >> 4;
    const int c0      = blockIdx.y * colspan;
    const int wr      = blockIdx.x * BM + wave * (NSETS * 16);

    // A fragments for NSETS row-tiles (coalesced: fragment-ordered global)
    bf16x8 a0[NSETS], a1[NSETS];
    #pragma unroll
    for (int s = 0; s < NSETS; ++s) {
        const char* ab = (const char*)z1f + (size_t)((wr >> 4) + s) * TILEB + lane * 16;
        a0[s] = *(const bf16x8*)(ab);
        a1[s] = *(const bf16x8*)(ab + 1024);
    }

    float sum[NSETS * 4];
    #pragma unroll
    for (int k = 0; k < NSETS * 4; ++k) sum[k] = 0.f;

    const char* bptr = (const char*)z2f + (size_t)(c0 >> 4) * TILEB + lane * 16;
    const f32x4 kzero = {0.f, 0.f, 0.f, 0.f};

    #pragma unroll 4
    for (int t = 0; t < ntiles; ++t) {
        bf16x8 b0 = *(const bf16x8*)(bptr);
        bf16x8 b1 = *(const bf16x8*)(bptr + 1024);
        bptr += TILEB;
        #pragma unroll
        for (int s = 0; s < NSETS; ++s) {
            f32x4 acc = __builtin_amdgcn_mfma_f32_16x16x32_bf16(a0[s], b0, kzero, 0, 0, 0);
            acc = __builtin_amdgcn_mfma_f32_16x16x32_bf16(a1[s], b1, acc, 0, 0, 0);
            sum[s * 4 + 0] += EXP2F(acc[0]);
            sum[s * 4 + 1] += EXP2F(acc[1]);
            sum[s * 4 + 2] += EXP2F(acc[2]);
            sum[s * 4 + 3] += EXP2F(acc[3]);
        }
    }

    // reduce each row-sum across the 16 lanes of the quad, then atomics
    #pragma unroll
    for (int k = 0; k < NSETS * 4; ++k) {
        float v = sum[k];
        #pragma unroll
        for (int o = 1; o < 16; o <<= 1) v += __shfl_xor(v, o);
        sum[k] = v;
    }
    if (l15 == 0) {
        #pragma unroll
        for (int s = 0; s < NSETS; ++s)
            #pragma unroll
            for (int i = 0; i < 4; ++i)
                atomicAdd(&rowsum[wr + s * 16 + q * 4 + i], sum[s * 4 + i]);
    }
}

// ---------------------------------------------------------------- finalize
// 64 blocks x 256 threads: thread t handles one row.
__global__ __launch_bounds__(256) void finalize_kernel(
    const float* __restrict__ rowsum, const float* __restrict__ posv,
    float* __restrict__ out, int N)
{
    int row = blockIdx.x * 256 + threadIdx.x;
    float acc = (LOG2F(rowsum[row]) - posv[row]) * (0.69314718055994531f / (float)N);
    #pragma unroll
    for (int o = 32; o; o >>= 1) acc += __shfl_xor(acc, o);
    if ((threadIdx.x & 63) == 0) atomicAdd(out, acc);
}

// ---------------------------------------------------------------- launch
extern "C" void kernel_launch(void* const* d_in, const int* in_sizes, int n_in,
                              void* d_out, int out_size, void* d_ws, size_t ws_size,
                              hipStream_t stream)
{
    const float* z1 = (const float*)d_in[0];
    const float* z2 = (const float*)d_in[1];
    const int N = in_sizes[0] / DDIM;   // 16384

    char* ws = (char*)d_ws;
    __hip_bfloat16* z1f = (__hip_bfloat16*)ws;                  // N*128 B (2 MB)
    __hip_bfloat16* z2f = z1f + (size_t)N * DDIM;               // N*128 B (2 MB)
    float* rowsum = (float*)(ws + 2 * (size_t)N * DDIM * 2);    // N*4 B
    float* posv   = rowsum + N;                                 // N*4 B

    const float kScale = 28.853900817779268f;   // log2(e) / 0.05

    norm_frag_kernel<<<N / 16, 256, 0, stream>>>(z1, z2, z1f, z2f, rowsum,
                                                 posv, (float*)d_out, kScale, N);

    dim3 grid(N / BM, CS);
    infonce_main_kernel<<<grid, NW * 64, 0, stream>>>(z1f, z2f, rowsum, N);

    finalize_kernel<<<N / 256, 256, 0, stream>>>(rowsum, posv, (float*)d_out, N);
}